// Round 2
// baseline (225.463 us; speedup 1.0000x reference)
//
#include <hip/hip_runtime.h>
#include <cmath>

#define T_LEN   480000
#define BATCH   64
#define CHUNK   16                       /* samples per thread */
#define WARM    16                       /* warm-up samples (|pole|=0.414 -> 0.414^16 ~ 7.6e-7) */
#define TPB     256
#define TS      (TPB * CHUNK)            /* 4096 samples per tile */
#define TPR     ((T_LEN + TS - 1) / TS)  /* 118 tiles per row */
#define TPB_TILES 4                      /* tiles per block (sequential, pipelined) */
#define BPR     ((TPR + TPB_TILES - 1) / TPB_TILES)   /* 30 blocks per row */
#define NLOAD_MAX (TS + WARM)            /* 4112 */
#define NITER   ((NLOAD_MAX + TPB * 4 - 1) / (TPB * 4))   /* 5 */
/* quad skew: +4 floats per 32 -> every aligned float4 stays contiguous,
   and all access patterns are exactly bank-uniform (8 lanes/quad). */
#define LDS_SLOTS (NLOAD_MAX + ((NLOAD_MAX >> 5) << 2))  /* 4624 = 18.5 KB */

__device__ __forceinline__ int slot4(int i) { return i + ((i >> 5) << 2); }

#define STEP(XN, YN)                                            \
    {                                                           \
        float u_ = fmaf(B0, (XN), fmaf(B1, x1, B2 * x2));       \
        (YN) = fmaf(-A1, y1, fmaf(-A2, y2, u_));                \
        x2 = x1; x1 = (XN); y2 = y1; y1 = (YN);                 \
    }

__global__ __launch_bounds__(TPB) void allpass_kernel(
    const float* __restrict__ x, float* __restrict__ y,
    float B0, float B1, float B2, float A1, float A2)
{
    __shared__ __align__(16) float lds[LDS_SLOTS];
    const int tid  = threadIdx.x;
    const int row  = blockIdx.x / BPR;
    const int tb0  = (blockIdx.x % BPR) * TPB_TILES;
    const int ntile = min(TPB_TILES, TPR - tb0);
    const float* __restrict__ xrow = x + (size_t)row * T_LEN;
    float* __restrict__ yrow       = y + (size_t)row * T_LEN;

    /* ---- prologue: prefetch tile tb0 into registers ---- */
    int sbase = tb0 * TS;
    int ns    = min(TS, T_LEN - sbase);
    int nload = ns + WARM;
    float4 vbuf[NITER];
    #pragma unroll
    for (int j = 0; j < NITER; ++j) {
        const int i4 = tid * 4 + j * (TPB * 4);
        if (i4 < nload) {
            if (tb0 == 0 && i4 < WARM)
                vbuf[j] = make_float4(0.f, 0.f, 0.f, 0.f); /* state before t=0 */
            else
                vbuf[j] = *(const float4*)(xrow + sbase - WARM + i4);
        }
    }

    /* ---- pipelined tile loop: commit regs->LDS, issue NEXT tile's global
       loads, then compute current tile.  Tile k+1's HBM latency hides under
       tile k's LDS reads + 32 STEPs + stores (T14 async-STAGE split). ---- */
    for (int it = 0; it < ntile; ++it) {
        #pragma unroll
        for (int j = 0; j < NITER; ++j) {
            const int i4 = tid * 4 + j * (TPB * 4);
            if (i4 < nload)
                *(float4*)&lds[slot4(i4)] = vbuf[j];   /* waits on vbuf loads */
        }
        __syncthreads();

        const int cur_sbase = sbase, cur_ns = ns;

        if (it + 1 < ntile) {               /* issue next tile's loads now */
            const int tb = tb0 + it + 1;
            sbase = tb * TS;
            ns    = min(TS, T_LEN - sbase);
            nload = ns + WARM;
            #pragma unroll
            for (int j = 0; j < NITER; ++j) {
                const int i4 = tid * 4 + j * (TPB * 4);
                if (i4 < nload)             /* tb>=1 here: no zero-fill path */
                    vbuf[j] = *(const float4*)(xrow + sbase - WARM + i4);
            }
        }

        /* compute: 16 warm-up + 16 real steps, direct register stores
           (a wave's 64B-stride float4 stores merge to full lines in L2 —
           verified round 1: WRITE_SIZE stayed at the ideal 120 MB). */
        const int ls = tid * CHUNK;
        if (ls < cur_ns) {
            float x1 = 0.f, x2 = 0.f, y1 = 0.f, y2 = 0.f;
            #pragma unroll
            for (int t4 = 0; t4 < WARM; t4 += 4) {
                float4 xv = *(const float4*)&lds[slot4(ls + t4)];
                float t;
                STEP(xv.x, t); STEP(xv.y, t); STEP(xv.z, t); STEP(xv.w, t);
            }
            #pragma unroll
            for (int t4 = 0; t4 < CHUNK; t4 += 4) {
                float4 xv = *(const float4*)&lds[slot4(ls + WARM + t4)];
                float4 yv;
                STEP(xv.x, yv.x); STEP(xv.y, yv.y);
                STEP(xv.z, yv.z); STEP(xv.w, yv.w);
                *(float4*)(yrow + cur_sbase + ls + t4) = yv;
            }
        }
        __syncthreads();   /* all LDS x-reads done before next commit */
    }
}

extern "C" void kernel_launch(void* const* d_in, const int* in_sizes, int n_in,
                              void* d_out, int out_size, void* d_ws, size_t ws_size,
                              hipStream_t stream) {
    const float* x = (const float*)d_in[0];
    float* y = (float*)d_out;

    const double sample_rate = 16000.0, central_freq = 4000.0, Q = 0.707;
    const double w0 = 2.0 * M_PI * central_freq / sample_rate;
    const double alpha = sin(w0) / (2.0 * Q);
    const double cw = cos(w0);
    const double a0 = 1.0 + alpha;
    const float B0 = (float)((1.0 - alpha) / a0);
    const float B1 = (float)((-2.0 * cw) / a0);
    const float B2 = (float)((1.0 + alpha) / a0);
    const float A1 = (float)((-2.0 * cw) / a0);
    const float A2 = (float)((1.0 - alpha) / a0);

    const int blocks = BATCH * BPR;   /* 1920: fully co-resident (7.5/CU) */
    allpass_kernel<<<blocks, TPB, 0, stream>>>(x, y, B0, B1, B2, A1, A2);
}